// Round 7
// baseline (99.798 us; speedup 1.0000x reference)
//
#include <hip/hip_runtime.h>

static constexpr int   Bn      = 32;
static constexpr int   Tn      = 2000;
static constexpr int   Hn      = 512;
static constexpr int   Ln      = 256;     // max_label_len
static constexpr float kThresh = 0.95f;
static constexpr int   TCHUNK  = 40;
static constexpr int   NTCH    = Tn / TCHUNK;   // 50

// ---------------------------------------------------------------------------
// K0 zero: grid-stride float4 zero of d_out (rocclr fill is slow/low-grid).
// ---------------------------------------------------------------------------
__global__ __launch_bounds__(256) void cif_zero_kernel(float4* __restrict__ p,
                                                       int n4) {
  const int stride = gridDim.x * blockDim.x;
  for (int i = blockIdx.x * blockDim.x + threadIdx.x; i < n4; i += stride)
    p[i] = make_float4(0.f, 0.f, 0.f, 0.f);
}

// ---------------------------------------------------------------------------
// K1 scan: one block (one wave) per batch row. The serial loop does ZERO
// memory operations except the double-buffered alpha prefetch: R4-R6 lesson —
// even one store per chunk forces a vmcnt(0) drain (store sources integrate/
// fc which the chain overwrites next instruction), exposing ~1 memory latency
// per 40-step chunk on a single wave. Instead, lane c captures the chunk-c
// boundary state via predicated selects (off the critical path; the 64
// redundant lanes each keep one snapshot in registers), and all 50 metas are
// written in ONE coalesced store after the loop.
// ---------------------------------------------------------------------------
__global__ __launch_bounds__(64) void cif_scan_kernel(
    const float* __restrict__ alphas,
    float2* __restrict__ meta,     // [Bn][NTCH]: chunk-start (integrate, bits(fc))
    int* __restrict__ fcnt) {      // [Bn]
  const int b    = blockIdx.x;
  const int lane = threadIdx.x;
  const float4* __restrict__ arow =
      reinterpret_cast<const float4*>(alphas + (size_t)b * Tn);
  constexpr int CV = TCHUNK / 4;   // 10 float4 per chunk

  float integrate = 0.0f;
  int   fc        = 0;
  float my_int    = 0.0f;          // lane `lane` snapshots chunk `lane`
  int   my_fc     = 0;

  float4 cur[CV], nxt[CV];
#pragma unroll
  for (int i = 0; i < CV; ++i) cur[i] = arow[i];

  for (int c = 0; c < NTCH; ++c) {
    if (c + 1 < NTCH) {
#pragma unroll
      for (int i = 0; i < CV; ++i) nxt[i] = arow[(c + 1) * CV + i];
    }
    // Register-only boundary capture (2 cndmasks, off the serial chain).
    const bool mine = (c == lane);
    my_int = mine ? integrate : my_int;
    my_fc  = mine ? fc        : my_fc;
#pragma unroll
    for (int i = 0; i < CV; ++i) {
      const float a4[4] = {cur[i].x, cur[i].y, cur[i].z, cur[i].w};
#pragma unroll
      for (int j = 0; j < 4; ++j) {
        const float integ = integrate + a4[j];    // reference op order
        const bool  fire  = integ > kThresh;
        integrate = fire ? (integ - 1.0f) : integ;
        fc += fire ? 1 : 0;
      }
    }
#pragma unroll
    for (int i = 0; i < CV; ++i) cur[i] = nxt[i];
  }

  if (lane < NTCH)
    meta[b * NTCH + lane] = make_float2(my_int, __int_as_float(my_fc));
  if (lane == 0) fcnt[b] = fc;
}

// ---------------------------------------------------------------------------
// K2 expand: 50 blocks (one per time-chunk); lane b replays the 40-step
// recurrence of row b from the BIT-EXACT chunk-start state and materializes
// per-step weights/segments in TIME-MAJOR layout (coalesced 256 B + 128 B
// stores per t across the 32 lanes). Parallel across chunks -> stores cheap.
// ---------------------------------------------------------------------------
__global__ __launch_bounds__(64) void cif_expand_kernel(
    const float* __restrict__ alphas,
    const float2* __restrict__ meta,
    float2* __restrict__ w12,      // [Tn][Bn]
    int* __restrict__ seg) {       // [Tn][Bn]
  const int tc = blockIdx.x;
  const int b  = threadIdx.x;
  if (b >= Bn) return;
  const int t0 = tc * TCHUNK;

  const float2 m  = meta[b * NTCH + tc];
  float integrate = m.x;
  int   fc        = __float_as_int(m.y);

  const float4* __restrict__ arow =
      reinterpret_cast<const float4*>(alphas + (size_t)b * Tn + t0);
  float av[TCHUNK];
#pragma unroll
  for (int i = 0; i < TCHUNK / 4; ++i) {
    const float4 v = arow[i];
    av[4 * i + 0] = v.x; av[4 * i + 1] = v.y;
    av[4 * i + 2] = v.z; av[4 * i + 3] = v.w;
  }

#pragma unroll
  for (int k = 0; k < TCHUNK; ++k) {
    const float a     = av[k];
    const float integ = integrate + a;            // reference op order
    const bool  fire  = integ > kThresh;
    const float cw    = fire ? (1.0f - integrate) : a;
    const float rem   = fire ? (a - cw) : 0.0f;
    w12[(size_t)(t0 + k) * Bn + b] = make_float2(cw, rem);
    seg[(size_t)(t0 + k) * Bn + b] = fc;
    integrate = fire ? (integ - 1.0f) : integ;
    fc += fire ? 1 : 0;
  }
}

// ---------------------------------------------------------------------------
// K3 accum: grid (B, NTCH) x 128 threads; each thread owns 4 consecutive
// floats of the H=512 row (coalesced float4). Segments monotone in t:
// accumulate in registers, flush on close. Only the chunk's first segment
// (receives previous chunk's tail) and the final open segment are shared ->
// atomicAdd; interior segments exclusive -> plain float4 store (out
// pre-zeroed). w12/seg reads are block-uniform broadcasts from L2.
// ---------------------------------------------------------------------------
__global__ __launch_bounds__(128) void cif_accum_kernel(
    const float* __restrict__ hidden,
    const float2* __restrict__ w12,   // [Tn][Bn]
    const int* __restrict__ seg,      // [Tn][Bn]
    const int* __restrict__ fcnt,
    float* __restrict__ out) {
  const int b   = blockIdx.x;
  const int tc  = blockIdx.y;
  const int t0  = tc * TCHUNK;
  const int t1  = t0 + TCHUNK;
  const int col = threadIdx.x * 4;

  const int fb    = fcnt[b];
  const int limit = fb < Ln ? fb : Ln;   // segments >= limit never emitted

  const float* hbase = hidden + (size_t)b * Tn * Hn + col;
  float*       obase = out    + (size_t)b * Ln * Hn + col;

  const int seg0 = seg[(size_t)t0 * Bn + b];

  float4 acc    = make_float4(0.f, 0.f, 0.f, 0.f);
  int    curseg = seg0;

  auto flush = [&](int sg, const float4& v, bool shared) {
    if (sg < limit) {
      float* o = obase + (size_t)sg * Hn;
      if (shared) {
        atomicAdd(o + 0, v.x);
        atomicAdd(o + 1, v.y);
        atomicAdd(o + 2, v.z);
        atomicAdd(o + 3, v.w);
      } else {
        *reinterpret_cast<float4*>(o) = v;   // exclusive: plain store
      }
    }
  };

  for (int t = t0; t < t1; ++t) {
    const int s = seg[(size_t)t * Bn + b];
    if (s != curseg) {               // fire with exactly-zero remainder
      flush(curseg, acc, curseg == seg0);
      acc    = make_float4(0.f, 0.f, 0.f, 0.f);
      curseg = s;
    }
    const float4 h = *reinterpret_cast<const float4*>(hbase + (size_t)t * Hn);
    const float2 w = w12[(size_t)t * Bn + b];
    acc.x += w.x * h.x;
    acc.y += w.x * h.y;
    acc.z += w.x * h.z;
    acc.w += w.x * h.w;
    if (w.y != 0.0f) {               // fire: close segment s, open s+1
      flush(s, acc, s == seg0);
      acc.x  = w.y * h.x;
      acc.y  = w.y * h.y;
      acc.z  = w.y * h.z;
      acc.w  = w.y * h.w;
      curseg = s + 1;
    }
  }
  flush(curseg, acc, true);          // open segment: may continue next chunk
}

extern "C" void kernel_launch(void* const* d_in, const int* in_sizes, int n_in,
                              void* d_out, int out_size, void* d_ws, size_t ws_size,
                              hipStream_t stream) {
  const float* hidden = (const float*)d_in[0];
  const float* alphas = (const float*)d_in[1];
  float* out = (float*)d_out;

  // ws layout: w12[T][B] float2 (512 KB) | seg[T][B] i32 (256 KB)
  //          | meta[B][NTCH] float2 (12.8 KB) | fcnt[B] i32
  float2* w12  = (float2*)d_ws;
  int*    segp = (int*)(w12 + (size_t)Bn * Tn);
  float2* meta = (float2*)(segp + (size_t)Bn * Tn);
  int*    fcnt = (int*)(meta + (size_t)Bn * NTCH);

  const int n4 = out_size / 4;   // 16.8 MB -> 1,048,576 float4s
  cif_zero_kernel<<<2048, 256, 0, stream>>>((float4*)out, n4);

  cif_scan_kernel<<<Bn, 64, 0, stream>>>(alphas, meta, fcnt);
  cif_expand_kernel<<<NTCH, 64, 0, stream>>>(alphas, meta, w12, segp);

  dim3 grid(Bn, NTCH);
  cif_accum_kernel<<<grid, 128, 0, stream>>>(hidden, w12, segp, fcnt, out);
}

// Round 8
// 78.417 us; speedup vs baseline: 1.2727x; 1.2727x over previous
//
#include <hip/hip_runtime.h>

static constexpr int   Bn      = 32;
static constexpr int   Tn      = 2000;
static constexpr int   Hn      = 512;
static constexpr int   Ln      = 256;     // max_label_len
static constexpr float kThresh = 0.95f;
static constexpr int   TCHUNK  = 40;
static constexpr int   NTCH    = Tn / TCHUNK;   // 50

// ---------------------------------------------------------------------------
// K1: scan + fire-table build in ONE dispatch, one wave per batch row.
// Phase A (all 64 lanes redundantly): R7's register-only serial recurrence —
// zero memory ops in the loop except the double-buffered alpha prefetch;
// lane c captures the chunk-c boundary state (integrate, fc) via predicated
// selects into its own registers.
// Phase B (lanes 0..49, no barrier needed — each lane uses only its own
// registers): lane c replays chunk c from its captured bit-exact state and
// writes one fire-table entry (t, cw, rem) per fire. ~250 entries/row.
// This removes the meta round-trip AND the separate expand dispatch.
// ---------------------------------------------------------------------------
__global__ __launch_bounds__(64) void cif_scan_table_kernel(
    const float* __restrict__ alphas,
    int*   __restrict__ tf,     // [Bn][Ln] fire timestep
    float* __restrict__ cwv,    // [Bn][Ln] closing weight (dist_completion)
    float* __restrict__ remv,   // [Bn][Ln] remainder weight (opens next seg)
    int*   __restrict__ fcnt) { // [Bn]
  const int b    = blockIdx.x;
  const int lane = threadIdx.x;
  const float4* __restrict__ arow =
      reinterpret_cast<const float4*>(alphas + (size_t)b * Tn);
  constexpr int CV = TCHUNK / 4;   // 10 float4 per chunk

  // ---- Phase A: serial scan, register-only (proven R7 structure) ----
  float integrate = 0.0f;
  int   fc        = 0;
  float my_int    = 0.0f;          // lane `lane` snapshots chunk `lane`
  int   my_fc     = 0;

  float4 cur[CV], nxt[CV];
#pragma unroll
  for (int i = 0; i < CV; ++i) cur[i] = arow[i];

  for (int c = 0; c < NTCH; ++c) {
    if (c + 1 < NTCH) {
#pragma unroll
      for (int i = 0; i < CV; ++i) nxt[i] = arow[(c + 1) * CV + i];
    }
    const bool mine = (c == lane);
    my_int = mine ? integrate : my_int;
    my_fc  = mine ? fc        : my_fc;
#pragma unroll
    for (int i = 0; i < CV; ++i) {
      const float a4[4] = {cur[i].x, cur[i].y, cur[i].z, cur[i].w};
#pragma unroll
      for (int j = 0; j < 4; ++j) {
        const float integ = integrate + a4[j];    // reference op order
        const bool  fire  = integ > kThresh;
        integrate = fire ? (integ - 1.0f) : integ;
        fc += fire ? 1 : 0;
      }
    }
#pragma unroll
    for (int i = 0; i < CV; ++i) cur[i] = nxt[i];
  }
  if (lane == 0) fcnt[b] = fc;

  // ---- Phase B: per-lane chunk replay -> fire table ----
  if (lane < NTCH) {
    const int t0 = lane * TCHUNK;
    const float4* __restrict__ crow =
        reinterpret_cast<const float4*>(alphas + (size_t)b * Tn + t0);
    float av[TCHUNK];
#pragma unroll
    for (int i = 0; i < CV; ++i) {
      const float4 v = crow[i];
      av[4 * i + 0] = v.x; av[4 * i + 1] = v.y;
      av[4 * i + 2] = v.z; av[4 * i + 3] = v.w;
    }
    float ig = my_int;
    int   s  = my_fc;
#pragma unroll
    for (int k = 0; k < TCHUNK; ++k) {
      const float a     = av[k];
      const float integ = ig + a;                 // reference op order
      const bool  fire  = integ > kThresh;
      if (fire) {
        if (s < Ln) {
          const float cw  = 1.0f - ig;            // dist_completion
          const float rem = a - cw;               // remainds
          tf  [b * Ln + s] = t0 + k;
          cwv [b * Ln + s] = cw;
          remv[b * Ln + s] = rem;
        }
        s += 1;
        ig = integ - 1.0f;
      } else {
        ig = integ;
      }
    }
  }
}

// ---------------------------------------------------------------------------
// K2: per-segment accumulation — block (s, b) EXCLUSIVELY owns out[b][s].
// Segment s spans (t_prev, t_hi]: acc = rem[s-1]*h[t_prev] (replace-open)
// + sum of raw alpha_t * h_t over interior t + cw[s]*h[t_hi], accumulated
// ascending in t (reference order). Plain float4 stores, NO atomics; blocks
// with s >= min(fcnt,Ln) store zeros — so NO pre-zero pass is needed and
// every output element is written exactly once per call (graph-replay safe).
// ---------------------------------------------------------------------------
__global__ __launch_bounds__(128) void cif_seg_accum_kernel(
    const float* __restrict__ hidden,
    const float* __restrict__ alphas,
    const int*   __restrict__ tf,
    const float* __restrict__ cwv,
    const float* __restrict__ remv,
    const int*   __restrict__ fcnt,
    float* __restrict__ out) {
  const int s   = blockIdx.x;          // 0..Ln-1
  const int b   = blockIdx.y;          // 0..Bn-1
  const int col = threadIdx.x * 4;

  const int fb    = fcnt[b];
  const int limit = fb < Ln ? fb : Ln;

  float* __restrict__ o = out + ((size_t)b * Ln + s) * Hn + col;

  if (s >= limit) {                    // never-fired slot: emit zeros
    *reinterpret_cast<float4*>(o) = make_float4(0.f, 0.f, 0.f, 0.f);
    return;
  }

  const int t_hi   = tf[b * Ln + s];
  const int t_prev = (s > 0) ? tf[b * Ln + s - 1] : -1;

  const float* __restrict__ hbase = hidden + (size_t)b * Tn * Hn + col;
  const float* __restrict__ arow  = alphas + (size_t)b * Tn;

  float4 acc = make_float4(0.f, 0.f, 0.f, 0.f);

  if (s > 0) {                         // opening: frame = rem * h[t_prev]
    const float r  = remv[b * Ln + s - 1];
    const float4 h = *reinterpret_cast<const float4*>(hbase + (size_t)t_prev * Hn);
    acc.x = r * h.x; acc.y = r * h.y; acc.z = r * h.z; acc.w = r * h.w;
  }
  for (int t = t_prev + 1; t < t_hi; ++t) {   // interior: weight = raw alpha
    const float a  = arow[t];
    const float4 h = *reinterpret_cast<const float4*>(hbase + (size_t)t * Hn);
    acc.x += a * h.x; acc.y += a * h.y; acc.z += a * h.z; acc.w += a * h.w;
  }
  {                                    // closing: weight = dist_completion
    const float c  = cwv[b * Ln + s];
    const float4 h = *reinterpret_cast<const float4*>(hbase + (size_t)t_hi * Hn);
    acc.x += c * h.x; acc.y += c * h.y; acc.z += c * h.z; acc.w += c * h.w;
  }
  *reinterpret_cast<float4*>(o) = acc;
}

extern "C" void kernel_launch(void* const* d_in, const int* in_sizes, int n_in,
                              void* d_out, int out_size, void* d_ws, size_t ws_size,
                              hipStream_t stream) {
  const float* hidden = (const float*)d_in[0];
  const float* alphas = (const float*)d_in[1];
  float* out = (float*)d_out;

  // ws layout: tf[B][Ln] i32 (32 KB) | cw[B][Ln] f32 | rem[B][Ln] f32 | fcnt[B]
  int*   tf   = (int*)d_ws;
  float* cwv  = (float*)(tf + (size_t)Bn * Ln);
  float* remv = cwv + (size_t)Bn * Ln;
  int*   fcnt = (int*)(remv + (size_t)Bn * Ln);

  cif_scan_table_kernel<<<Bn, 64, 0, stream>>>(alphas, tf, cwv, remv, fcnt);

  dim3 grid(Ln, Bn);   // 8192 independent blocks, one per output slot
  cif_seg_accum_kernel<<<grid, 128, 0, stream>>>(hidden, alphas, tf, cwv,
                                                 remv, fcnt, out);
}